// Round 8
// baseline (389.081 us; speedup 1.0000x reference)
//
#include <hip/hip_runtime.h>

#define HW 512
#define NPIX (HW*HW)
#define NSAMP 64
#define KSEL 2621
#define NF 3
#define NQ (NF*NSAMP)
#define CAP 16384
#define CPAD 32     // count padding (uints) -> 128B per counter, no false sharing

#define HALO 3      // max filter halo
#define LSTR 520    // LDS row stride in floats (16B-aligned, bank-friendly)
#define ROWS 16     // strip rows (R7 lesson: ROWS=8 raised overhead, no stall fix)
#define TR (ROWS + 2*HALO)   // 22

// Sample bracket ranks (of 32768 samples): expected population counts
// nA ~ 8*rank. Margins are ~6 sigma even with chunk-correlation inflation;
// exactness does NOT depend on them (fallback path).
#define RANK_HI 8
#define RANK_LO 980

// ===========================================================================
// Row-streaming conv (round-5 lesson: small live set, no spills).
// ===========================================================================
template<int K, int R>
__device__ __forceinline__ void conv_rows_f64(
    const float (*xt)[LSTR], const double* __restrict__ wsm,
    int tx, double* __restrict__ acc)
{
  constexpr int ROFF = HALO - K/2;
  constexpr int COFF = 4 - K/2;
  #pragma unroll
  for (int y = 0; y < R + K - 1; ++y) {
    double v[K];
    #pragma unroll
    for (int j = 0; j < K; ++j)
      v[j] = (double)xt[y + ROFF][tx + j + COFF];
    #pragma unroll
    for (int i = 0; i < K; ++i) {
      const int r = y - i;                 // compile-time after unroll
      if (r >= 0 && r < R) {
        #pragma unroll
        for (int j = 0; j < K; ++j)
          acc[r] = fma(v[j], wsm[i*K + j], acc[r]);
      }
    }
  }
}

template<int K, int R>
__device__ __forceinline__ void conv_rows_f32(
    const float (*xt)[LSTR], const float* __restrict__ wsm,
    int tx, float* __restrict__ acc)
{
  constexpr int ROFF = HALO - K/2;
  constexpr int COFF = 4 - K/2;
  #pragma unroll
  for (int y = 0; y < R + K - 1; ++y) {
    float v[K];
    #pragma unroll
    for (int j = 0; j < K; ++j)
      v[j] = xt[y + ROFF][tx + j + COFF];
    #pragma unroll
    for (int i = 0; i < K; ++i) {
      const int r = y - i;
      if (r >= 0 && r < R) {
        #pragma unroll
        for (int j = 0; j < K; ++j)
          acc[r] = fmaf(v[j], wsm[i*K + j], acc[r]);
      }
    }
  }
}

// Descending scan of a 2048-bin LDS hist: find bin containing the kr-th
// largest; coarse-256 + fine-8 (serial-2048 by one thread is ~130cyc/dep-read
// latency-bound). All threads enter; result left in shared outs.
__device__ __forceinline__ void scan2048_desc(
    const unsigned* lh, unsigned* part, int t, unsigned kr,
    unsigned* out_bin, unsigned* out_krem)
{
  unsigned sum = 0;
  #pragma unroll
  for (int i = 0; i < 8; ++i) sum += lh[t*8 + i];
  part[t] = sum;
  __syncthreads();
  if (t == 0) {
    unsigned cum = 0; int sc = 0;
    for (int c = 255; c >= 0; --c) {
      if (cum + part[c] >= kr) { sc = c; break; }
      cum += part[c];
    }
    unsigned cum2 = cum; int sb = sc*8;
    for (int b = sc*8 + 7; b >= sc*8; --b) {
      if (cum2 + lh[b] >= kr) { sb = b; break; }
      cum2 += lh[b];
    }
    *out_bin = (unsigned)sb; *out_krem = kr - cum2;
  }
  __syncthreads();
}

__device__ __forceinline__ void scan512_desc(
    const unsigned* lh, unsigned* part, int t, unsigned kr,
    unsigned* out_bin)
{
  part[t] = lh[2*t] + lh[2*t + 1];
  __syncthreads();
  if (t == 0) {
    unsigned cum = 0; int sc = 0;
    for (int c = 255; c >= 0; --c) {
      if (cum + part[c] >= kr) { sc = c; break; }
      cum += part[c];
    }
    unsigned cum2 = cum; int sb = 2*sc;
    for (int b = 2*sc + 1; b >= 2*sc; --b) {
      if (cum2 + lh[b] >= kr) { sb = b; break; }
      cum2 += lh[b];
    }
    *out_bin = (unsigned)sb;
  }
  __syncthreads();
}

// ===========================================================================
// Forward: pure fp64 conv (exact selection vs reference), NO histogram
// (round-7 lesson: 50M Gaussian-concentrated LDS hist atomics serialize
// ~16-way in the shared DS pipe -> ~60-90us; moved to sample+count path).
// ===========================================================================
__global__ __launch_bounds__(512, 2) void fwd_all(
    const float* __restrict__ x,
    const float* __restrict__ w3, const float* __restrict__ w5,
    const float* __restrict__ w7,
    float* __restrict__ sims)
{
  __shared__ float xt[TR][LSTR];
  __shared__ double wsm[49];

  const int tid = threadIdx.x;
  const int s  = blockIdx.y;
  const int by = blockIdx.x * ROWS;
  const float* __restrict__ xs = x + (size_t)s*NPIX;

  // zero x-halo pads: cols 0..3 and 516..519
  if (tid < TR*8) {
    const int r = tid >> 3, c = tid & 7;
    xt[r][(c < 4) ? c : 512 + c] = 0.0f;
  }
  // stage TR rows x 128 float4 (data at float offset 4 -> 16B aligned)
  for (int idx = tid; idx < TR*128; idx += 512) {
    const int r = idx >> 7, c4 = idx & 127;
    const int gy = by + r - HALO;
    float4 v = make_float4(0.f, 0.f, 0.f, 0.f);
    if (gy >= 0 && gy < HW)
      v = ((const float4*)(xs + (size_t)gy*HW))[c4];
    *(float4*)&xt[r][4 + 4*c4] = v;
  }

  const int tx = tid;
  const float* const wp[NF] = {w3, w5, w7};

  #pragma unroll
  for (int f = 0; f < NF; ++f) {
    if (tid < 49) wsm[tid] = (tid < (3+2*f)*(3+2*f)) ? (double)wp[f][tid] : 0.0;
    __syncthreads();                    // staging/prev-conv done, wsm ready

    double acc[ROWS];
    #pragma unroll
    for (int r = 0; r < ROWS; ++r) acc[r] = 0.0;
    if (f == 0)      conv_rows_f64<3, ROWS>(xt, wsm, tx, acc);
    else if (f == 1) conv_rows_f64<5, ROWS>(xt, wsm, tx, acc);
    else             conv_rows_f64<7, ROWS>(xt, wsm, tx, acc);

    float* __restrict__ so =
        sims + ((size_t)f*NSAMP + s)*NPIX + (size_t)by*HW + tx;
    #pragma unroll
    for (int r = 0; r < ROWS; ++r)
      so[(size_t)r*HW] = (float)acc[r];
    __syncthreads();                    // conv done before wsm rewrite
  }
}

// ===========================================================================
// Sample: per q, 128 chunks x 256 contiguous floats (coalesced, 32768
// samples), coarse hist of bits[30:20], bracket thresholds at sample ranks
// RANK_HI / RANK_LO from the top.
// ===========================================================================
__global__ __launch_bounds__(256) void sample_all(
    const float* __restrict__ sims, unsigned* __restrict__ tlo,
    unsigned* __restrict__ thi)
{
  __shared__ unsigned lh[2048];
  __shared__ unsigned part[256];
  __shared__ unsigned sbin, skrem;
  const int q = blockIdx.x, t = threadIdx.x;
  for (int i = t; i < 2048; i += 256) lh[i] = 0;
  __syncthreads();

  const float* __restrict__ sq = sims + (size_t)q*NPIX;
  for (int rep = 0; rep < 128; ++rep) {
    const unsigned b = __float_as_uint(sq[rep*2048 + t]) & 0x7fffffffu;
    atomicAdd(&lh[b >> 20], 1u);
  }
  __syncthreads();

  scan2048_desc(lh, part, t, RANK_HI, &sbin, &skrem);
  const unsigned bhi = sbin;
  scan2048_desc(lh, part, t, RANK_LO, &sbin, &skrem);
  const unsigned blo = sbin;
  if (t == 0) {
    unsigned Th = (bhi == blo) ? ((bhi + 1u) << 20) : (bhi << 20);
    tlo[q] = blo << 20;
    thi[q] = Th;
  }
}

// ===========================================================================
// Count + compact: one streaming pass over sims. Per-thread register count
// of bits >= T_hi (zero atomics), shfl-reduced, ONE global atomic per block;
// candidates in [T_lo, T_hi) via block-local LDS aggregation + one padded
// global atomic (round-3 lesson).
// ===========================================================================
__global__ __launch_bounds__(256) void count_compact(
    const float* __restrict__ sims, const unsigned* __restrict__ tlo,
    const unsigned* __restrict__ thi, unsigned* __restrict__ cntA,
    unsigned* __restrict__ cntC, unsigned* __restrict__ cand)
{
  __shared__ unsigned sb[4096];
  __shared__ unsigned scnt, sbase, sA;
  const int tid = threadIdx.x;
  const int q = blockIdx.y;
  if (tid == 0) { scnt = 0; sA = 0; }
  __syncthreads();

  const unsigned Tl = tlo[q], Th = thi[q];
  const float4* __restrict__ p =
      (const float4*)(sims + (size_t)q*NPIX) + (size_t)blockIdx.x*1024;
  unsigned ca = 0;
  #pragma unroll
  for (int k = 0; k < 4; ++k) {
    const float4 v = p[k*256 + tid];
    const float f4[4] = {v.x, v.y, v.z, v.w};
    #pragma unroll
    for (int e = 0; e < 4; ++e) {
      const unsigned bits = __float_as_uint(f4[e]) & 0x7fffffffu;
      ca += (bits >= Th);
      if (bits >= Tl && bits < Th) {
        const unsigned pos = atomicAdd(&scnt, 1u);
        if (pos < 4096) sb[pos] = bits;
      }
    }
  }
  // wave-reduce ca, one LDS atomic per wave
  #pragma unroll
  for (int o = 32; o > 0; o >>= 1) ca += __shfl_down(ca, o);
  if ((tid & 63) == 0 && ca) atomicAdd(&sA, ca);
  __syncthreads();

  const unsigned nb = scnt;
  if (tid == 0) {
    if (sA) atomicAdd(&cntA[(size_t)q*CPAD], sA);
    sbase = nb ? atomicAdd(&cntC[(size_t)q*CPAD], nb) : 0u;
    if (nb > 4096) atomicAdd(&cntC[(size_t)q*CPAD], (unsigned)(CAP + 1)); // poison -> fallback
  }
  __syncthreads();
  const unsigned base = sbase;
  const unsigned nstore = (nb < 4096u) ? nb : 4096u;
  for (unsigned i = tid; i < nstore; i += 256) {
    const unsigned pos = base + i;
    if (pos < CAP) cand[(size_t)q*CAP + pos] = sb[i];
  }
}

// ===========================================================================
// Exact selection: kth-largest-overall = (KSEL-nA)th largest in C (A = all
// bits >= T_hi, counted exactly). 3-level radix on the compact list; full
// plane fallback if bracket invalid/overflow. thb = kth largest bit pattern;
// kept = bits >= thb (ties kept, matching jnp >= semantics).
// ===========================================================================
__global__ __launch_bounds__(256) void sel_final(
    const unsigned* __restrict__ cntA, const unsigned* __restrict__ cntC,
    const unsigned* __restrict__ cand, const float* __restrict__ sims,
    unsigned* __restrict__ thb)
{
  __shared__ unsigned lh[2048];
  __shared__ unsigned part[256];
  __shared__ unsigned sbin, skrem;
  const int q = blockIdx.x, t = threadIdx.x;

  const unsigned nA = cntA[(size_t)q*CPAD];
  const unsigned nC = cntC[(size_t)q*CPAD];
  const unsigned* __restrict__ cq = cand + (size_t)q*CAP;
  const float*    __restrict__ sq = sims + (size_t)q*NPIX;
  const bool ok = (nA < KSEL) && (nA + nC >= KSEL) && (nC <= CAP);
  const unsigned kr0 = ok ? (KSEL - nA) : (unsigned)KSEL;

  // ---- level 1: bits[30:20] ----
  for (int i = t; i < 2048; i += 256) lh[i] = 0;
  __syncthreads();
  if (ok) {
    for (unsigned i = t; i < nC; i += 256) atomicAdd(&lh[cq[i] >> 20], 1u);
  } else {
    for (int i = t; i < NPIX; i += 256) {
      const unsigned b = __float_as_uint(sq[i]) & 0x7fffffffu;
      atomicAdd(&lh[b >> 20], 1u);
    }
  }
  __syncthreads();
  scan2048_desc(lh, part, t, kr0, &sbin, &skrem);
  const unsigned pfx1 = sbin << 20;
  const unsigned kr1  = skrem;

  // ---- level 2: bits[19:9] ----
  for (int i = t; i < 2048; i += 256) lh[i] = 0;
  __syncthreads();
  if (ok) {
    for (unsigned i = t; i < nC; i += 256) {
      const unsigned b = cq[i];
      if ((b >> 20) == (pfx1 >> 20)) atomicAdd(&lh[(b >> 9) & 0x7ffu], 1u);
    }
  } else {
    for (int i = t; i < NPIX; i += 256) {
      const unsigned b = __float_as_uint(sq[i]) & 0x7fffffffu;
      if ((b >> 20) == (pfx1 >> 20)) atomicAdd(&lh[(b >> 9) & 0x7ffu], 1u);
    }
  }
  __syncthreads();
  scan2048_desc(lh, part, t, kr1, &sbin, &skrem);
  const unsigned pfx2 = pfx1 | (sbin << 9);
  const unsigned kr2  = skrem;

  // ---- level 3: bits[8:0] ----
  for (int i = t; i < 512; i += 256) lh[i] = 0;
  __syncthreads();
  if (ok) {
    for (unsigned i = t; i < nC; i += 256) {
      const unsigned b = cq[i];
      if ((b >> 9) == (pfx2 >> 9)) atomicAdd(&lh[b & 0x1ffu], 1u);
    }
  } else {
    for (int i = t; i < NPIX; i += 256) {
      const unsigned b = __float_as_uint(sq[i]) & 0x7fffffffu;
      if ((b >> 9) == (pfx2 >> 9)) atomicAdd(&lh[b & 0x1ffu], 1u);
    }
  }
  __syncthreads();
  scan512_desc(lh, part, t, kr2, &sbin);
  if (t == 0) thb[q] = pfx2 | sbin;
}

// ===========================================================================
// Backward: per 512x16 strip, stage thresholded sim_f (coalesced float4),
// row-streaming fp32 conv, accumulate across filters, single out write.
// ===========================================================================
__global__ __launch_bounds__(512, 2) void bwd_all(
    const float* __restrict__ sims,
    const float* __restrict__ w3, const float* __restrict__ w5,
    const float* __restrict__ w7,
    const unsigned* __restrict__ thb, float* __restrict__ out)
{
  __shared__ float xt[TR][LSTR];
  __shared__ float wsm[49];

  const int tid = threadIdx.x;
  const int s  = blockIdx.y;
  const int by = blockIdx.x * ROWS;
  const int tx = tid;
  const float* const wp[NF] = {w3, w5, w7};

  if (tid < TR*8) {
    const int r = tid >> 3, c = tid & 7;
    xt[r][(c < 4) ? c : 512 + c] = 0.0f;
  }

  float acc[ROWS];
  #pragma unroll
  for (int r = 0; r < ROWS; ++r) acc[r] = 0.0f;

  #pragma unroll
  for (int f = 0; f < NF; ++f) {
    __syncthreads();                    // pads done / prev conv done
    if (tid < 49) wsm[tid] = (tid < (3+2*f)*(3+2*f)) ? wp[f][tid] : 0.0f;
    const unsigned th = thb[f*NSAMP + s];
    const float* __restrict__ ss = sims + ((size_t)f*NSAMP + s)*NPIX;

    for (int idx = tid; idx < TR*128; idx += 512) {
      const int r = idx >> 7, c4 = idx & 127;
      const int gy = by + r - HALO;
      float4 v = make_float4(0.f, 0.f, 0.f, 0.f);
      if (gy >= 0 && gy < HW) {
        v = ((const float4*)(ss + (size_t)gy*HW))[c4];
        if ((__float_as_uint(v.x) & 0x7fffffffu) < th) v.x = 0.0f;
        if ((__float_as_uint(v.y) & 0x7fffffffu) < th) v.y = 0.0f;
        if ((__float_as_uint(v.z) & 0x7fffffffu) < th) v.z = 0.0f;
        if ((__float_as_uint(v.w) & 0x7fffffffu) < th) v.w = 0.0f;
      }
      *(float4*)&xt[r][4 + 4*c4] = v;
    }
    __syncthreads();

    if (f == 0)      conv_rows_f32<3, ROWS>(xt, wsm, tx, acc);
    else if (f == 1) conv_rows_f32<5, ROWS>(xt, wsm, tx, acc);
    else             conv_rows_f32<7, ROWS>(xt, wsm, tx, acc);
  }

  float* __restrict__ oo = out + (size_t)s*NPIX + (size_t)by*HW + tx;
  #pragma unroll
  for (int r = 0; r < ROWS; ++r)
    oo[(size_t)r*HW] = acc[r];
}

// ===========================================================================
extern "C" void kernel_launch(void* const* d_in, const int* in_sizes, int n_in,
                              void* d_out, int out_size, void* d_ws, size_t ws_size,
                              hipStream_t stream)
{
  const float* x  = (const float*)d_in[0];
  const float* w3 = (const float*)d_in[1];
  const float* w5 = (const float*)d_in[2];
  const float* w7 = (const float*)d_in[3];
  float* out = (float*)d_out;
  char* ws = (char*)d_ws;

  const size_t SIMS_B = (size_t)NF*NSAMP*NPIX*sizeof(float);   // 192 MB
  const size_t CNT_B  = (size_t)NQ*CPAD*sizeof(unsigned);      // 24 KB each

  float*    sims = (float*)ws;
  unsigned* cntA = (unsigned*)(ws + SIMS_B);
  unsigned* cntC = cntA + (size_t)NQ*CPAD;
  unsigned* tlo  = cntC + (size_t)NQ*CPAD;
  unsigned* thi  = tlo + NQ;
  unsigned* thb  = thi + NQ;
  unsigned* cand = thb + NQ + NQ;      // spare NQ gap

  hipMemsetAsync(cntA, 0, 2*CNT_B, stream);   // cntA + cntC contiguous

  dim3 b512(512, 1, 1);
  dim3 sg(HW/ROWS, NSAMP, 1);          // 32 x 64 strips
  fwd_all<<<sg, b512, 0, stream>>>(x, w3, w5, w7, sims);
  sample_all<<<NQ, 256, 0, stream>>>(sims, tlo, thi);
  dim3 rg(NPIX/4096, NQ, 1);
  count_compact<<<rg, dim3(256,1,1), 0, stream>>>(sims, tlo, thi, cntA, cntC, cand);
  sel_final<<<NQ, 256, 0, stream>>>(cntA, cntC, cand, sims, thb);
  bwd_all<<<sg, b512, 0, stream>>>(sims, w3, w5, w7, thb, out);
}